// Round 11
// baseline (180.425 us; speedup 1.0000x reference)
//
#include <hip/hip_runtime.h>
#include <math.h>

#define TOKENS 32768
#define RDIM 512
#define NEXP 64
#define NK 256
#define LDQ 136            // fallback w-plane LDS row stride (ushorts)
#define PSTR 67            // logit plane row stride (words)
#define TAU 4.0e-3f        // top-2/3 boundary guard band (~60x worst-case bf16x3 logit error)

typedef unsigned short u16;
typedef float f32x4 __attribute__((ext_vector_type(4)));
typedef short s16x8 __attribute__((ext_vector_type(8)));

#define MFMA_B16(a, b, c) __builtin_amdgcn_mfma_f32_16x16x32_bf16(a, b, c, 0, 0, 0)

// async 16B global->LDS copy: LDS dest = (wave-uniform base) + lane*16, global src per-lane.
__device__ __forceinline__ void gload_lds16(const u16* g, u16* l) {
    __builtin_amdgcn_global_load_lds(
        (const __attribute__((address_space(1))) void*)g,
        (__attribute__((address_space(3))) void*)l, 16, 0, 0);
}

// Truncating hi/lo bf16 split of 4 floats, packed pairwise into uints (k-ascending).
__device__ __forceinline__ void split_pack(float4 v, unsigned& h01, unsigned& h23,
                                           unsigned& l01, unsigned& l23) {
    unsigned u0 = __float_as_uint(v.x), u1 = __float_as_uint(v.y);
    unsigned u2 = __float_as_uint(v.z), u3 = __float_as_uint(v.w);
    float r0 = v.x - __uint_as_float(u0 & 0xFFFF0000u);
    float r1 = v.y - __uint_as_float(u1 & 0xFFFF0000u);
    float r2 = v.z - __uint_as_float(u2 & 0xFFFF0000u);
    float r3 = v.w - __uint_as_float(u3 & 0xFFFF0000u);
    h01 = (u0 >> 16) | (u1 & 0xFFFF0000u);
    h23 = (u2 >> 16) | (u3 & 0xFFFF0000u);
    l01 = (__float_as_uint(r0) >> 16) | (__float_as_uint(r1) & 0xFFFF0000u);
    l23 = (__float_as_uint(r2) >> 16) | (__float_as_uint(r3) & 0xFFFF0000u);
}

// 8 floats -> bf16-hi frag + bf16-lo frag, in registers.
__device__ __forceinline__ void split8(float4 a, float4 b, s16x8& hi, s16x8& lo) {
    union U { unsigned u[4]; s16x8 v; };
    U H, L;
    split_pack(a, H.u[0], H.u[1], L.u[0], L.u[1]);
    split_pack(b, H.u[2], H.u[3], L.u[2], L.u[3]);
    hi = H.v; lo = L.v;
}

// Centroid body: one (expert e, r-half) pair, 256 threads, pack[] in LDS.
__device__ __forceinline__ void centroid_body(
    int e, int half, int tid,
    const float* __restrict__ atoms, const float* __restrict__ cw,
    const float* __restrict__ cl, float* __restrict__ cent, unsigned* pack)
{
    {   // one k per thread (256 threads == NK)
        const int k = tid;
        unsigned u = 0;
        float w3[3];
        #pragma unroll
        for (int xx = 0; xx < 3; ++xx) {
            const float* cp = cl + ((((size_t)e * NK + k) * 3 + xx) << 4);
            float v[16];
            *(float4*)(v + 0)  = *(const float4*)(cp + 0);
            *(float4*)(v + 4)  = *(const float4*)(cp + 4);
            *(float4*)(v + 8)  = *(const float4*)(cp + 8);
            *(float4*)(v + 12) = *(const float4*)(cp + 12);
            float best = v[0]; int bi = 0;
            #pragma unroll
            for (int a = 1; a < 16; ++a) {          // strict > keeps first max (jnp.argmax)
                if (v[a] > best) { best = v[a]; bi = a; }
            }
            u |= (unsigned)bi << (4 * xx);
            w3[xx] = cw[((size_t)e * NK + k) * 3 + xx];
        }
        unsigned lut = 0;
        #pragma unroll
        for (int c = 0; c < 8; ++c) {
            float val = ((c & 1) ? -w3[0] : w3[0])
                      + ((c & 2) ? -w3[1] : w3[1])
                      + ((c & 4) ? -w3[2] : w3[2]);
            lut |= (val < 0.f ? 1u : 0u) << c;
        }
        pack[k] = u | (lut << 16);
    }

    const int r = half * 256 + tid;
    unsigned B0 = 0;
    #pragma unroll
    for (int a = 0; a < 16; ++a)
        B0 |= (atoms[((size_t)e * 16 + a) * RDIM + r] < 0.f ? 1u : 0u) << a;
    __syncthreads();

    int n0 = 0;
    #pragma unroll 2
    for (int k = 0; k < NK; k += 8) {               // 8-wide batched broadcast reads
        unsigned pk8[8];
        #pragma unroll
        for (int j = 0; j < 8; ++j) pk8[j] = pack[k + j];
        #pragma unroll
        for (int j = 0; j < 8; ++j) {
            unsigned u  = pk8[j];
            unsigned i0 = u & 15u, i1 = (u >> 4) & 15u, i2 = (u >> 8) & 15u;
            unsigned c0 = ((B0 >> i0) & 1u) | (((B0 >> i1) & 1u) << 1) | (((B0 >> i2) & 1u) << 2);
            n0 += (u >> (16 + c0)) & 1u;
        }
    }
    cent[(size_t)e * RDIM + r] = 1.f - (float)n0 * (1.f / 128.f);
}

// ---------------- Kernel A-fast: centroids (blocks 0-127) + w hi/lo frag-pack (128-159) ----
// pk layout (ushorts): pk[((g*4+kg)*64 + row)*8 + j], g=k>>5, kg=(k>>3)&3, j=k&7
// -> pk[...] = w[row][k] as bf16 hi/lo. A K-quarter (4 g's) is one contiguous 16KB slab.
__global__ __launch_bounds__(256) void centroid_pack_kernel(
    const float* __restrict__ atoms,
    const float* __restrict__ cw,
    const float* __restrict__ cl,
    const float* __restrict__ w,
    float* __restrict__ cent,
    u16* __restrict__ pk_hi,
    u16* __restrict__ pk_lo,
    float* __restrict__ aux_sum,
    unsigned* __restrict__ aux_cnt)
{
    __shared__ unsigned pack[NK];
    const int tid = threadIdx.x;
    if (blockIdx.x == 0 && tid < 64) { aux_sum[tid] = 0.f; aux_cnt[tid] = 0u; }

    if (blockIdx.x < 128) {
        centroid_body(blockIdx.x >> 1, blockIdx.x & 1, tid, atoms, cw, cl, cent, pack);
    } else {
        const int gid = (blockIdx.x - 128) * 256 + tid;     // 0..8191, 4 elems each
        const int row = gid >> 7;                           // 128 threads per 512-float row
        const int k0  = (gid & 127) * 4;
        const int g   = k0 >> 5, kg = (k0 >> 3) & 3, j = k0 & 7;   // j in {0,4}
        const int idx = ((g * 4 + kg) * 64 + row) * 8 + j;
        float4 wv = *(const float4*)(w + (size_t)row * RDIM + k0);
        unsigned h01, h23, l01, l23;
        split_pack(wv, h01, h23, l01, l23);
        *(uint2*)&pk_hi[idx] = make_uint2(h01, h23);
        *(uint2*)&pk_lo[idx] = make_uint2(l01, l23);
    }
}

// ---------------- Kernel B-fast5: 8-waves/SIMD DMA-staged GEMM + MoE epilogue -------------
// Grid 1024 x 512 thr = 4 blocks/CU (LDS 33KB, __launch_bounds__(512,8) -> VGPR<=64,
// which R10 PROVED this code body fits) = 32 waves/CU = 8 waves/SIMD -- 2x R10's hiding.
// Tile 32 tok x 64 exp; wave wv = (tokG=wv>>2, expG=wv&3) owns 16 tok x 16 exp (one f32x4).
// w staged per K-QUARTER via async global_load_lds from the pre-converted frag-ordered pk
// planes (zero staging VALU/ds_write); x from global with a 3-deep compile-time ring.
// Verified MFMA mapping: A row=l15(token), B row=l15(expert), k=(lane>>4)*8+j;
// C col=lane&15 (expert), row=(lane>>4)*4+i (token).
__global__ __launch_bounds__(512, 8) void moe_fast5(
    const float* __restrict__ x,
    const u16* __restrict__ pk_hi,
    const u16* __restrict__ pk_lo,
    const float* __restrict__ w,
    const float* __restrict__ cent,
    float* __restrict__ out,
    float* __restrict__ aux_sum,
    unsigned* __restrict__ aux_cnt)
{
    __shared__ __align__(16) u16 wlds[16384];   // 32KB: hi quarter 16KB + lo quarter 16KB
    u16* whi = wlds;
    u16* wlo = wlds + 8192;
    // epilogue overlays (staging dead by then; ~24KB used of 32KB)
    float* P     = (float*)wlds;                // [32][PSTR] logits -> probs in place
    float* candv = P + 32 * PSTR;               // [32][49] (16 slices x top-3, padded)
    int*   candi = (int*)(candv + 32 * 49);
    float* qsum  = (float*)(candi + 32 * 49);   // [32][17]
    float* gateL = qsum + 32 * 17;              // [32][4]: g1,g2,bitcast(e1),bitcast(e2)
    __shared__ float s_aux[64];
    __shared__ unsigned s_cnt[64];

    const int tid  = threadIdx.x;
    const int lane = tid & 63;
    const int wv   = tid >> 6;             // wave 0..7
    const int tokG = wv >> 2;              // 0..1
    const int expG = wv & 3;               // 0..3
    const int l15  = lane & 15;
    const int kq   = lane >> 4;            // 0..3
    const int kgrp = kq << 3;
    const int tok0 = blockIdx.x * 32;

    if (tid < 64) { s_aux[tid] = 0.f; s_cnt[tid] = 0u; }

    f32x4 acc = (f32x4){0.f, 0.f, 0.f, 0.f};

    // A path: lane's own token row (4 expG waves share rows -> L1 reuse)
    const float* xlane = x + (size_t)(tok0 + tokG * 16 + l15) * RDIM + kgrp;
    // staging: wave wv owns ushort range [wv*1024, wv*1024+1024) of each plane's quarter
    const int wbase = wv * 1024;
    // frag base (ushorts) within a (g,kq)-slab for this wave's expert group
    const int fb = (expG * 16 + l15) * 8;

    // x ring, depth 3, compile-time g%3 indexing (fully unrolled loops)
    float4 preA[3], preB[3];
    #pragma unroll
    for (int i = 0; i < 3; ++i) {
        preA[i] = *(const float4*)(xlane + i * 32);
        preB[i] = *(const float4*)(xlane + i * 32 + 4);
    }

    #pragma unroll
    for (int q = 0; q < 4; ++q) {
        if (q) __syncthreads();            // prior quarter's B-frag reads done
        {   // async-stage this K-quarter's pk slabs: 4 x 1KB DMA per wave, zero VALU
            const u16* sh = pk_hi + q * 8192 + wbase + lane * 8;
            const u16* sl = pk_lo + q * 8192 + wbase + lane * 8;
            gload_lds16(sh,       whi + wbase);
            gload_lds16(sh + 512, whi + wbase + 512);
            gload_lds16(sl,       wlo + wbase);
            gload_lds16(sl + 512, wlo + wbase + 512);
        }
        __syncthreads();                   // compiler-emitted vmcnt(0) drains the DMAs

        #pragma unroll
        for (int kb = 0; kb < 4; ++kb) {   // 4 K32 steps per quarter
            const int g = q * 4 + kb;
            s16x8 ah, al;
            split8(preA[g % 3], preB[g % 3], ah, al);
            if (g + 3 < 16) {              // ring refill flows across quarter boundaries
                const float* nx = xlane + (g + 3) * 32;
                preA[g % 3] = *(const float4*)(nx);
                preB[g % 3] = *(const float4*)(nx + 4);
            }
            const int fq = (kb * 4 + kq) * 512 + fb;
            s16x8 bh = *(const s16x8*)&whi[fq];
            s16x8 bl = *(const s16x8*)&wlo[fq];
            acc = MFMA_B16(ah, bh, acc);   // hi*hi
            acc = MFMA_B16(ah, bl, acc);   // hi*lo
            acc = MFMA_B16(al, bh, acc);   // lo*hi
        }
    }

    // ---- logits to LDS plane [32 tok][PSTR] ----
    __syncthreads();                       // last quarter's frag reads done before overlay
    #pragma unroll
    for (int i = 0; i < 4; ++i)
        P[(tokG * 16 + kq * 4 + i) * PSTR + expG * 16 + l15] = acc[i];
    __syncthreads();

    // ---- E1: per (token tt, slice ss) local top-3 over 4 experts ----
    const int tt = tid & 31;
    const int ss = tid >> 5;               // 0..15
    float v[4];
    #pragma unroll
    for (int j = 0; j < 4; ++j) v[j] = P[tt * PSTR + ss * 4 + j];

    float m1 = -INFINITY, m2 = -INFINITY, m3 = -INFINITY;
    int   i1 = NEXP, i2 = NEXP, i3 = NEXP;
    #pragma unroll
    for (int j = 0; j < 4; ++j) {          // ascending e + strict > == lax.top_k tie-break
        float val = v[j]; int e = ss * 4 + j;
        if (val > m1)      { m3 = m2; i3 = i2; m2 = m1; i2 = i1; m1 = val; i1 = e; }
        else if (val > m2) { m3 = m2; i3 = i2; m2 = val; i2 = e; }
        else if (val > m3) { m3 = val; i3 = e; }
    }
    candv[tt * 49 + ss * 3 + 0] = m1; candi[tt * 49 + ss * 3 + 0] = i1;
    candv[tt * 49 + ss * 3 + 1] = m2; candi[tt * 49 + ss * 3 + 1] = i2;
    candv[tt * 49 + ss * 3 + 2] = m3; candi[tt * 49 + ss * 3 + 2] = i3;
    __syncthreads();

    // ---- E2: merge 48 candidates (slice-ascending insertion keeps low-index ties first) ----
    m1 = m2 = m3 = -INFINITY; i1 = i2 = i3 = NEXP;
    #pragma unroll 4
    for (int q = 0; q < 48; ++q) {
        float val = candv[tt * 49 + q]; int e = candi[tt * 49 + q];
        if (val > m1)      { m3 = m2; i3 = i2; m2 = m1; i2 = i1; m1 = val; i1 = e; }
        else if (val > m2) { m3 = m2; i3 = i2; m2 = val; i2 = e; }
        else if (val > m3) { m3 = val; i3 = e; }
    }

    float ex[4]; float ps = 0.f;
    #pragma unroll
    for (int j = 0; j < 4; ++j) { ex[j] = __expf(v[j] - m1); ps += ex[j]; }
    qsum[tt * 17 + ss] = ps;

    if (wv == 0) {                         // wave 0: gates + cooperative guard re-rank
        if (lane < 32) {                   // lanes<32: tt == lane
            const float ed  = __expf(m2 - m1);
            const float inv = 1.f / (1.f + ed);
            gateL[tt * 4 + 0] = inv;
            gateL[tt * 4 + 1] = ed * inv;
            ((int*)gateL)[tt * 4 + 2] = i1;
            ((int*)gateL)[tt * 4 + 3] = i2;
        }
        // near top-2/3 boundary: exact f32 re-rank, 64-lane cooperative per flagged token
        unsigned long long bmask = __ballot(lane < 32 && (m2 - m3 < TAU));
        while (bmask) {
            const int f = __ffsll(bmask) - 1;   // flagged token (lane==tt for lane<32)
            bmask &= bmask - 1;
            int id3[3];
            id3[0] = __shfl(i1, f); id3[1] = __shfl(i2, f); id3[2] = __shfl(i3, f);
            const float* xrow = x + (size_t)(tok0 + f) * RDIM + lane * 8;
            float4 a0 = *(const float4*)(xrow);
            float4 a1 = *(const float4*)(xrow + 4);
            float d[3];
            #pragma unroll
            for (int jj = 0; jj < 3; ++jj) {
                const float* wrow = w + (size_t)id3[jj] * RDIM + lane * 8;
                float4 b0 = *(const float4*)(wrow);
                float4 b1 = *(const float4*)(wrow + 4);
                float p = a0.x * b0.x;
                p = fmaf(a0.y, b0.y, p); p = fmaf(a0.z, b0.z, p); p = fmaf(a0.w, b0.w, p);
                p = fmaf(a1.x, b1.x, p); p = fmaf(a1.y, b1.y, p);
                p = fmaf(a1.z, b1.z, p); p = fmaf(a1.w, b1.w, p);
                #pragma unroll
                for (int off = 32; off; off >>= 1) p += __shfl_xor(p, off);
                d[jj] = p;
            }
            int b = 0;
            if (d[1] > d[0] || (d[1] == d[0] && id3[1] < id3[0])) b = 1;
            if (d[2] > d[b] || (d[2] == d[b] && id3[2] < id3[b])) b = 2;
            int sec;
            if (b == 0)      sec = (d[1] > d[2] || (d[1] == d[2] && id3[1] < id3[2])) ? 1 : 2;
            else if (b == 1) sec = (d[0] > d[2] || (d[0] == d[2] && id3[0] < id3[2])) ? 0 : 2;
            else             sec = (d[0] > d[1] || (d[0] == d[1] && id3[0] < id3[1])) ? 0 : 1;
            if (lane == f) {
                const float ed  = __expf(d[sec] - d[b]);
                const float inv = 1.f / (1.f + ed);
                gateL[f * 4 + 0] = inv;
                gateL[f * 4 + 1] = ed * inv;
                ((int*)gateL)[f * 4 + 2] = id3[b];
                ((int*)gateL)[f * 4 + 3] = id3[sec];
            }
        }
    }
    __syncthreads();

    // ---- E3: softmax denominator + probs in place ----
    float Z = 0.f;
    #pragma unroll
    for (int k = 0; k < 16; ++k) Z += qsum[tt * 17 + k];
    const float invZ = 1.f / Z;
    #pragma unroll
    for (int j = 0; j < 4; ++j) P[tt * PSTR + ss * 4 + j] = ex[j] * invZ;
    __syncthreads();

    // ---- E4: per-expert column sums for aux (8 token-groups of 4) ----
    {
        const int e = tid & 63, tq = tid >> 6;
        float s = 0.f; unsigned cn = 0u;
        #pragma unroll
        for (int t = 0; t < 4; ++t) {
            float pv = P[(tq * 4 + t) * PSTR + e];
            s += pv; cn += (pv > 0.f) ? 1u : 0u;
        }
        atomicAdd(&s_aux[e], s);
        atomicAdd(&s_cnt[e], cn);
    }
    __syncthreads();
    if (tid < 64) {
        atomicAdd(aux_sum + tid, s_aux[tid]);
        atomicAdd(aux_cnt + tid, s_cnt[tid]);
    }

    // ---- OUT: wave handles 4 tokens, lane = r-chunk (coalesced 1KB stores) ----
    {
        const int e = lane;
        #pragma unroll
        for (int s2 = 0; s2 < 4; ++s2) {
            const int t2 = wv * 4 + s2;
            float4 g4 = *(float4*)&gateL[t2 * 4];       // broadcast read
            const float g1 = g4.x, g2 = g4.y;
            const int e1 = __float_as_int(g4.z), e2 = __float_as_int(g4.w);
            const float4* c1 = (const float4*)(cent + (size_t)e1 * RDIM);
            const float4* c2 = (const float4*)(cent + (size_t)e2 * RDIM);
            float4* op = (float4*)(out + (size_t)(tok0 + t2) * RDIM);
            float4 A0 = c1[e],      Bb0 = c2[e];
            float4 A1 = c1[e + 64], Bb1 = c2[e + 64];
            float4 o0, o1;
            o0.x = fmaf(g1, A0.x, g2 * Bb0.x); o0.y = fmaf(g1, A0.y, g2 * Bb0.y);
            o0.z = fmaf(g1, A0.z, g2 * Bb0.z); o0.w = fmaf(g1, A0.w, g2 * Bb0.w);
            o1.x = fmaf(g1, A1.x, g2 * Bb1.x); o1.y = fmaf(g1, A1.y, g2 * Bb1.y);
            o1.z = fmaf(g1, A1.z, g2 * Bb1.z); o1.w = fmaf(g1, A1.w, g2 * Bb1.w);
            op[e]      = o0;
            op[e + 64] = o1;
        }
    }
}

// ---------------- Fallback kernels (used only if ws too small) ----------------
__global__ __launch_bounds__(256) void centroid_kernel(
    const float* __restrict__ atoms,
    const float* __restrict__ cw,
    const float* __restrict__ cl,
    float* __restrict__ cent,
    float* __restrict__ aux_sum,
    unsigned* __restrict__ aux_cnt)
{
    __shared__ unsigned pack[NK];
    const int tid = threadIdx.x;
    if (blockIdx.x == 0 && tid < 64) { aux_sum[tid] = 0.f; aux_cnt[tid] = 0u; }
    centroid_body(blockIdx.x >> 1, blockIdx.x & 1, tid, atoms, cw, cl, cent, pack);
}

__global__ __launch_bounds__(256, 4) void moe_main(
    const float* __restrict__ x,
    const float* __restrict__ w,
    const float* __restrict__ cent,
    float* __restrict__ out,
    float* __restrict__ aux_sum,
    unsigned* __restrict__ aux_cnt)
{
    __shared__ u16 wlds[2 * 64 * LDQ];
    u16* whi = wlds;
    u16* wlo = wlds + 64 * LDQ;
    float* P     = (float*)wlds;
    float* candv = P + 64 * PSTR;
    int*   candi = (int*)(candv + 64 * 13);
    float* qsum  = (float*)(candi + 64 * 13);
    float* gateL = qsum + 64 * 5;
    __shared__ float s_aux[64];
    __shared__ unsigned s_cnt[64];

    const int tid  = threadIdx.x;
    const int lane = tid & 63;
    const int wave = tid >> 6;
    const int l15  = lane & 15;
    const int kgrp = (lane >> 4) << 3;
    const int tok0 = blockIdx.x * 64;

    if (tid < 64) { s_aux[tid] = 0.f; s_cnt[tid] = 0u; }

    f32x4 acc[4];
    #pragma unroll
    for (int nt = 0; nt < 4; ++nt) acc[nt] = (f32x4){0.f, 0.f, 0.f, 0.f};

    const float* xlane = x + (size_t)(tok0 + wave * 16 + l15) * RDIM + kgrp;
    const int wrow = tid >> 2;
    const int wseg = tid & 3;
    const float* wg = w + (size_t)wrow * RDIM + wseg * 32;
    const int woff = wrow * LDQ + wseg * 32;

    float4 preA[4], preB[4];
    #pragma unroll
    for (int i = 0; i < 4; ++i) {
        preA[i] = *(const float4*)(xlane + i * 32);
        preB[i] = *(const float4*)(xlane + i * 32 + 4);
    }

    #pragma unroll
    for (int q = 0; q < 4; ++q) {
        if (q) __syncthreads();
        {
            const float* wq = wg + q * 128;
            uint2 h2[2], l2[2];
            #pragma unroll
            for (int j = 0; j < 8; ++j) {
                float4 wvv = *(const float4*)(wq + j * 4);
                split_pack(wvv, h2[j & 1].x, h2[j & 1].y, l2[j & 1].x, l2[j & 1].y);
                if (j & 1) {
                    *(uint4*)&whi[woff + (j - 1) * 4] =
                        make_uint4(h2[0].x, h2[0].y, h2[1].x, h2[1].y);
                    *(uint4*)&wlo[woff + (j - 1) * 4] =
                        make_uint4(l2[0].x, l2[0].y, l2[1].x, l2[1].y);
                }
            }
        }
        __syncthreads();

        #pragma unroll
        for (int kb = 0; kb < 4; ++kb) {
            const int g = q * 4 + kb;
            s16x8 ah, al;
            split8(preA[g & 3], preB[g & 3], ah, al);
            if (g + 4 < 16) {
                const float* nx = xlane + (g + 4) * 32;
                preA[g & 3] = *(const float4*)(nx);
                preB[g & 3] = *(const float4*)(nx + 4);
            }
            const int kl = kb * 32 + kgrp;
            #pragma unroll
            for (int nt = 0; nt < 4; ++nt) {
                const int brow = nt * 16 + l15;
                s16x8 bh = *(const s16x8*)&whi[brow * LDQ + kl];
                s16x8 bl = *(const s16x8*)&wlo[brow * LDQ + kl];
                acc[nt] = MFMA_B16(ah, bh, acc[nt]);
                acc[nt] = MFMA_B16(ah, bl, acc[nt]);
                acc[nt] = MFMA_B16(al, bh, acc[nt]);
            }
        }
    }

    __syncthreads();
    #pragma unroll
    for (int nt = 0; nt < 4; ++nt)
        #pragma unroll
        for (int i = 0; i < 4; ++i)
            P[(wave * 16 + ((lane >> 4) << 2) + i) * PSTR + nt * 16 + l15] = acc[nt][i];
    __syncthreads();

    const int tt = tid & 63;
    const int ss = tid >> 6;
    float v[16];
    #pragma unroll
    for (int j = 0; j < 16; ++j) v[j] = P[tt * PSTR + ss * 16 + j];

    float m1 = -INFINITY, m2 = -INFINITY, m3 = -INFINITY;
    int   i1 = NEXP, i2 = NEXP, i3 = NEXP;
    #pragma unroll
    for (int j = 0; j < 16; ++j) {
        float val = v[j]; int e = ss * 16 + j;
        if (val > m1)      { m3 = m2; i3 = i2; m2 = m1; i2 = i1; m1 = val; i1 = e; }
        else if (val > m2) { m3 = m2; i3 = i2; m2 = val; i2 = e; }
        else if (val > m3) { m3 = val; i3 = e; }
    }
    candv[tt * 13 + ss * 3 + 0] = m1; candi[tt * 13 + ss * 3 + 0] = i1;
    candv[tt * 13 + ss * 3 + 1] = m2; candi[tt * 13 + ss * 3 + 1] = i2;
    candv[tt * 13 + ss * 3 + 2] = m3; candi[tt * 13 + ss * 3 + 2] = i3;
    __syncthreads();

    m1 = m2 = m3 = -INFINITY; i1 = i2 = i3 = NEXP;
    #pragma unroll
    for (int q = 0; q < 12; ++q) {
        float val = candv[tt * 13 + q]; int e = candi[tt * 13 + q];
        if (val > m1)      { m3 = m2; i3 = i2; m2 = m1; i2 = i1; m1 = val; i1 = e; }
        else if (val > m2) { m3 = m2; i3 = i2; m2 = val; i2 = e; }
        else if (val > m3) { m3 = val; i3 = e; }
    }

    float ex[16]; float ps = 0.f;
    #pragma unroll
    for (int j = 0; j < 16; ++j) { ex[j] = __expf(v[j] - m1); ps += ex[j]; }
    qsum[tt * 5 + ss] = ps;

    if (ss == 0) {
        {
            const float ed  = __expf(m2 - m1);
            const float inv = 1.f / (1.f + ed);
            gateL[tt * 4 + 0] = inv;
            gateL[tt * 4 + 1] = ed * inv;
            ((int*)gateL)[tt * 4 + 2] = i1;
            ((int*)gateL)[tt * 4 + 3] = i2;
        }
        unsigned long long bmask = __ballot(m2 - m3 < TAU);
        while (bmask) {
            const int f = __ffsll(bmask) - 1;
            bmask &= bmask - 1;
            int id3[3];
            id3[0] = __shfl(i1, f); id3[1] = __shfl(i2, f); id3[2] = __shfl(i3, f);
            const float* xrow = x + (size_t)(tok0 + f) * RDIM + lane * 8;
            float4 a0 = *(const float4*)(xrow);
            float4 a1 = *(const float4*)(xrow + 4);
            float d[3];
            #pragma unroll
            for (int jj = 0; jj < 3; ++jj) {
                const float* wrow2 = w + (size_t)id3[jj] * RDIM + lane * 8;
                float4 b0 = *(const float4*)(wrow2);
                float4 b1 = *(const float4*)(wrow2 + 4);
                float p = a0.x * b0.x;
                p = fmaf(a0.y, b0.y, p); p = fmaf(a0.z, b0.z, p); p = fmaf(a0.w, b0.w, p);
                p = fmaf(a1.x, b1.x, p); p = fmaf(a1.y, b1.y, p);
                p = fmaf(a1.z, b1.z, p); p = fmaf(a1.w, b1.w, p);
                #pragma unroll
                for (int off = 32; off; off >>= 1) p += __shfl_xor(p, off);
                d[jj] = p;
            }
            int b = 0;
            if (d[1] > d[0] || (d[1] == d[0] && id3[1] < id3[0])) b = 1;
            if (d[2] > d[b] || (d[2] == d[b] && id3[2] < id3[b])) b = 2;
            int sec;
            if (b == 0)      sec = (d[1] > d[2] || (d[1] == d[2] && id3[1] < id3[2])) ? 1 : 2;
            else if (b == 1) sec = (d[0] > d[2] || (d[0] == d[2] && id3[0] < id3[2])) ? 0 : 2;
            else             sec = (d[0] > d[1] || (d[0] == d[1] && id3[0] < id3[1])) ? 0 : 1;
            if (lane == f) {
                const float ed  = __expf(d[sec] - d[b]);
                const float inv = 1.f / (1.f + ed);
                gateL[f * 4 + 0] = inv;
                gateL[f * 4 + 1] = ed * inv;
                ((int*)gateL)[f * 4 + 2] = id3[b];
                ((int*)gateL)[f * 4 + 3] = id3[sec];
            }
        }
    }
    __syncthreads();

    float Z = 0.f;
    #pragma unroll
    for (int k = 0; k < 4; ++k) Z += qsum[tt * 5 + k];
    const float invZ = 1.f / Z;
    #pragma unroll
    for (int j = 0; j < 16; ++j) P[tt * PSTR + ss * 16 + j] = ex[j] * invZ;
    __syncthreads();

    {
        const int e = tid & 63, tq = tid >> 6;
        float s = 0.f; unsigned cn = 0u;
        #pragma unroll
        for (int t = 0; t < 16; ++t) {
            float pv = P[(tq * 16 + t) * PSTR + e];
            s += pv; cn += (pv > 0.f) ? 1u : 0u;
        }
        atomicAdd(&s_aux[e], s);
        atomicAdd(&s_cnt[e], cn);
    }
    __syncthreads();
    if (tid < 64) {
        atomicAdd(aux_sum + tid, s_aux[tid]);
        atomicAdd(aux_cnt + tid, s_cnt[tid]);
    }

    {
        const int e = lane;
        #pragma unroll
        for (int s2 = 0; s2 < 16; ++s2) {
            const int t2 = wave * 16 + s2;
            float4 g4 = *(float4*)&gateL[t2 * 4];
            const float g1 = g4.x, g2 = g4.y;
            const int e1 = __float_as_int(g4.z), e2 = __float_as_int(g4.w);
            const float4* c1 = (const float4*)(cent + (size_t)e1 * RDIM);
            const float4* c2 = (const float4*)(cent + (size_t)e2 * RDIM);
            float4* op = (float4*)(out + (size_t)(tok0 + t2) * RDIM);
            float4 A0 = c1[e],      Bb0 = c2[e];
            float4 A1 = c1[e + 64], Bb1 = c2[e + 64];
            float4 o0, o1;
            o0.x = fmaf(g1, A0.x, g2 * Bb0.x); o0.y = fmaf(g1, A0.y, g2 * Bb0.y);
            o0.z = fmaf(g1, A0.z, g2 * Bb0.z); o0.w = fmaf(g1, A0.w, g2 * Bb0.w);
            o1.x = fmaf(g1, A1.x, g2 * Bb1.x); o1.y = fmaf(g1, A1.y, g2 * Bb1.y);
            o1.z = fmaf(g1, A1.z, g2 * Bb1.z); o1.w = fmaf(g1, A1.w, g2 * Bb1.w);
            op[e]      = o0;
            op[e + 64] = o1;
        }
    }
}

// ---------------- Kernel C: aux loss finalize ----------------
__global__ __launch_bounds__(64) void aux_kernel(
    const float* __restrict__ sums,
    const unsigned* __restrict__ cnts,
    float* __restrict__ out_aux)
{
    const int e = threadIdx.x;
    float v = (sums[e] * (1.f / (float)TOKENS)) * ((float)cnts[e] * (1.f / (float)TOKENS));
    #pragma unroll
    for (int off = 32; off; off >>= 1) v += __shfl_xor(v, off);
    if (e == 0) out_aux[0] = (float)NEXP * v;
}

extern "C" void kernel_launch(void* const* d_in, const int* in_sizes, int n_in,
                              void* d_out, int out_size, void* d_ws, size_t ws_size,
                              hipStream_t stream) {
    const float* x     = (const float*)d_in[0];  // (8,4096,512)
    const float* rw    = (const float*)d_in[1];  // (64,512)
    const float* atoms = (const float*)d_in[2];  // (64,16,512)
    const float* cwts  = (const float*)d_in[3];  // (64,256,3)
    const float* clog  = (const float*)d_in[4];  // (64,256,3,16)
    float* out = (float*)d_out;
    float* out_aux = out + (size_t)TOKENS * RDIM;

    // ws: aux_sum[64]@0, aux_cnt[64]@256, cent@512 (128KB), pk_hi@131584 (64KB), pk_lo@197120
    float*    aux_sum = (float*)d_ws;
    unsigned* aux_cnt = (unsigned*)((char*)d_ws + 256);
    float*    cent    = (float*)((char*)d_ws + 512);
    u16*      pk_hi   = (u16*)((char*)d_ws + 512 + 131072);
    u16*      pk_lo   = (u16*)((char*)d_ws + 512 + 131072 + 65536);
    const bool fast = ws_size >= (size_t)(512 + 131072 + 2 * 65536);

    if (fast) {
        centroid_pack_kernel<<<160, 256, 0, stream>>>(atoms, cwts, clog, rw, cent,
                                                      pk_hi, pk_lo, aux_sum, aux_cnt);
        moe_fast5<<<1024, 512, 0, stream>>>(x, pk_hi, pk_lo, rw, cent, out, aux_sum, aux_cnt);
    } else {
        centroid_kernel<<<128, 256, 0, stream>>>(atoms, cwts, clog, cent, aux_sum, aux_cnt);
        moe_main<<<512, 256, 0, stream>>>(x, rw, cent, out, aux_sum, aux_cnt);
    }
    aux_kernel<<<1, 64, 0, stream>>>(aux_sum, aux_cnt, out_aux);
}

// Round 12
// 153.723 us; speedup vs baseline: 1.1737x; 1.1737x over previous
//
#include <hip/hip_runtime.h>
#include <math.h>

#define TOKENS 32768
#define RDIM 512
#define NEXP 64
#define NK 256
#define LDQ 136            // fallback w-plane LDS row stride (ushorts)
#define PSTR 67            // logit plane row stride (words)
#define TAU 4.0e-3f        // top-2/3 boundary guard band (~60x worst-case bf16x3 logit error)

typedef unsigned short u16;
typedef float f32x4 __attribute__((ext_vector_type(4)));
typedef short s16x8 __attribute__((ext_vector_type(8)));

#define MFMA_B16(a, b, c) __builtin_amdgcn_mfma_f32_16x16x32_bf16(a, b, c, 0, 0, 0)

// async 16B global->LDS copy: LDS dest = (wave-uniform base) + lane*16, global src per-lane.
__device__ __forceinline__ void gload_lds16(const u16* g, u16* l) {
    __builtin_amdgcn_global_load_lds(
        (const __attribute__((address_space(1))) void*)g,
        (__attribute__((address_space(3))) void*)l, 16, 0, 0);
}

// Truncating hi/lo bf16 split of 4 floats, packed pairwise into uints (k-ascending).
__device__ __forceinline__ void split_pack(float4 v, unsigned& h01, unsigned& h23,
                                           unsigned& l01, unsigned& l23) {
    unsigned u0 = __float_as_uint(v.x), u1 = __float_as_uint(v.y);
    unsigned u2 = __float_as_uint(v.z), u3 = __float_as_uint(v.w);
    float r0 = v.x - __uint_as_float(u0 & 0xFFFF0000u);
    float r1 = v.y - __uint_as_float(u1 & 0xFFFF0000u);
    float r2 = v.z - __uint_as_float(u2 & 0xFFFF0000u);
    float r3 = v.w - __uint_as_float(u3 & 0xFFFF0000u);
    h01 = (u0 >> 16) | (u1 & 0xFFFF0000u);
    h23 = (u2 >> 16) | (u3 & 0xFFFF0000u);
    l01 = (__float_as_uint(r0) >> 16) | (__float_as_uint(r1) & 0xFFFF0000u);
    l23 = (__float_as_uint(r2) >> 16) | (__float_as_uint(r3) & 0xFFFF0000u);
}

// 8 floats -> bf16-hi frag + bf16-lo frag, in registers.
__device__ __forceinline__ void split8(float4 a, float4 b, s16x8& hi, s16x8& lo) {
    union U { unsigned u[4]; s16x8 v; };
    U H, L;
    split_pack(a, H.u[0], H.u[1], L.u[0], L.u[1]);
    split_pack(b, H.u[2], H.u[3], L.u[2], L.u[3]);
    hi = H.v; lo = L.v;
}

// Centroid body: one (expert e, r-half) pair, 256 threads, pack[] in LDS.
__device__ __forceinline__ void centroid_body(
    int e, int half, int tid,
    const float* __restrict__ atoms, const float* __restrict__ cw,
    const float* __restrict__ cl, float* __restrict__ cent, unsigned* pack)
{
    {   // one k per thread (256 threads == NK)
        const int k = tid;
        unsigned u = 0;
        float w3[3];
        #pragma unroll
        for (int xx = 0; xx < 3; ++xx) {
            const float* cp = cl + ((((size_t)e * NK + k) * 3 + xx) << 4);
            float v[16];
            *(float4*)(v + 0)  = *(const float4*)(cp + 0);
            *(float4*)(v + 4)  = *(const float4*)(cp + 4);
            *(float4*)(v + 8)  = *(const float4*)(cp + 8);
            *(float4*)(v + 12) = *(const float4*)(cp + 12);
            float best = v[0]; int bi = 0;
            #pragma unroll
            for (int a = 1; a < 16; ++a) {          // strict > keeps first max (jnp.argmax)
                if (v[a] > best) { best = v[a]; bi = a; }
            }
            u |= (unsigned)bi << (4 * xx);
            w3[xx] = cw[((size_t)e * NK + k) * 3 + xx];
        }
        unsigned lut = 0;
        #pragma unroll
        for (int c = 0; c < 8; ++c) {
            float val = ((c & 1) ? -w3[0] : w3[0])
                      + ((c & 2) ? -w3[1] : w3[1])
                      + ((c & 4) ? -w3[2] : w3[2]);
            lut |= (val < 0.f ? 1u : 0u) << c;
        }
        pack[k] = u | (lut << 16);
    }

    const int r = half * 256 + tid;
    unsigned B0 = 0;
    #pragma unroll
    for (int a = 0; a < 16; ++a)
        B0 |= (atoms[((size_t)e * 16 + a) * RDIM + r] < 0.f ? 1u : 0u) << a;
    __syncthreads();

    int n0 = 0;
    #pragma unroll 2
    for (int k = 0; k < NK; k += 8) {               // 8-wide batched broadcast reads
        unsigned pk8[8];
        #pragma unroll
        for (int j = 0; j < 8; ++j) pk8[j] = pack[k + j];
        #pragma unroll
        for (int j = 0; j < 8; ++j) {
            unsigned u  = pk8[j];
            unsigned i0 = u & 15u, i1 = (u >> 4) & 15u, i2 = (u >> 8) & 15u;
            unsigned c0 = ((B0 >> i0) & 1u) | (((B0 >> i1) & 1u) << 1) | (((B0 >> i2) & 1u) << 2);
            n0 += (u >> (16 + c0)) & 1u;
        }
    }
    cent[(size_t)e * RDIM + r] = 1.f - (float)n0 * (1.f / 128.f);
}

// ---------------- Kernel A-fast: centroids (blocks 0-127) + w hi/lo frag-pack (128-159) ----
// pk layout (ushorts): pk[((g*4+kg)*64 + row)*8 + j], g=k>>5, kg=(k>>3)&3, j=k&7
// -> pk[...] = w[row][k] as bf16 hi/lo. A K-half (g in [8h,8h+8)) is one contiguous 32KB slab.
__global__ __launch_bounds__(256) void centroid_pack_kernel(
    const float* __restrict__ atoms,
    const float* __restrict__ cw,
    const float* __restrict__ cl,
    const float* __restrict__ w,
    float* __restrict__ cent,
    u16* __restrict__ pk_hi,
    u16* __restrict__ pk_lo,
    float* __restrict__ aux_sum,
    unsigned* __restrict__ aux_cnt)
{
    __shared__ unsigned pack[NK];
    const int tid = threadIdx.x;
    if (blockIdx.x == 0 && tid < 64) { aux_sum[tid] = 0.f; aux_cnt[tid] = 0u; }

    if (blockIdx.x < 128) {
        centroid_body(blockIdx.x >> 1, blockIdx.x & 1, tid, atoms, cw, cl, cent, pack);
    } else {
        const int gid = (blockIdx.x - 128) * 256 + tid;     // 0..8191, 4 elems each
        const int row = gid >> 7;                           // 128 threads per 512-float row
        const int k0  = (gid & 127) * 4;
        const int g   = k0 >> 5, kg = (k0 >> 3) & 3, j = k0 & 7;   // j in {0,4}
        const int idx = ((g * 4 + kg) * 64 + row) * 8 + j;
        float4 wv = *(const float4*)(w + (size_t)row * RDIM + k0);
        unsigned h01, h23, l01, l23;
        split_pack(wv, h01, h23, l01, l23);
        *(uint2*)&pk_hi[idx] = make_uint2(h01, h23);
        *(uint2*)&pk_lo[idx] = make_uint2(l01, l23);
    }
}

// ---------------- Kernel B-fast4: R3-best structure + global_load_lds staging --------------
// Session-best configuration (R10, 154.5us total): 512 blocks x 512 thr, 2 blocks/CU,
// 4 waves/SIMD; tile 64 tok x 64 exp; wave (tokG,expG) owns 16 tok x 32 exp; 3 barriers.
// w staging = 8 async global_load_lds(16B) per wave per K-half from the pre-converted
// frag-ordered pk planes -> zero staging VALU, zero ds_write, no VGPR round-trip.
// LDS image == pk slab (linear), frag ds_read_b128 = 8 acc/bank = conflict-free.
// 8-waves/SIMD variants (R8, R11) both collapse: allocator halves VGPR below need -> spills.
// Verified MFMA mapping: A row=l15(token), B row=l15(expert), k=(lane>>4)*8+j;
// C col=lane&15 (expert), row=(lane>>4)*4+i (token).
__global__ __launch_bounds__(512, 4) void moe_fast4(
    const float* __restrict__ x,
    const u16* __restrict__ pk_hi,
    const u16* __restrict__ pk_lo,
    const float* __restrict__ w,
    const float* __restrict__ cent,
    float* __restrict__ out,
    float* __restrict__ aux_sum,
    unsigned* __restrict__ aux_cnt)
{
    __shared__ __align__(16) u16 wlds[32768];   // 64KB: hi plane 32KB + lo plane 32KB
    u16* whi = wlds;
    u16* wlo = wlds + 16384;
    // epilogue overlays (staging dead by then; ~33KB used of 64KB)
    float* P     = (float*)wlds;                // [64][PSTR] logits -> probs in place
    float* candv = P + 64 * PSTR;               // [64][25] (8 slices x top-3, padded)
    int*   candi = (int*)(candv + 64 * 25);
    float* qsum  = (float*)(candi + 64 * 25);   // [64][9]
    float* gateL = qsum + 64 * 9;               // [64][4]: g1,g2,bitcast(e1),bitcast(e2)
    __shared__ float s_aux[64];
    __shared__ unsigned s_cnt[64];

    const int tid  = threadIdx.x;
    const int lane = tid & 63;
    const int wv   = tid >> 6;             // wave 0..7
    const int tokG = wv >> 1;              // 0..3
    const int expG = wv & 1;               // 0..1
    const int l15  = lane & 15;
    const int kq   = lane >> 4;            // 0..3
    const int kgrp = kq << 3;
    const int tok0 = blockIdx.x * 64;

    if (tid < 64) { s_aux[tid] = 0.f; s_cnt[tid] = 0u; }

    f32x4 acc[2];
    acc[0] = (f32x4){0.f, 0.f, 0.f, 0.f};
    acc[1] = (f32x4){0.f, 0.f, 0.f, 0.f};

    // A path: lane's own token row
    const float* xlane = x + (size_t)(tok0 + tokG * 16 + l15) * RDIM + kgrp;
    // staging: wave wv owns ushort range [wv*2048, wv*2048+2048) of each 16384-ushort plane
    const int wbase = wv * 2048;
    // frag base (ushorts) within a (kb,kq)-slab for this wave's nt=0 expert row
    const int fb = (expG * 32 + l15) * 8;

    #pragma unroll
    for (int h = 0; h < 2; ++h) {
        // issue x prefetch (k-steps 0..2 of this half) before staging, hides under it
        const float* xb = xlane + h * 256;
        float4 p0a = *(const float4*)(xb);      float4 p0b = *(const float4*)(xb + 4);
        float4 p1a = *(const float4*)(xb + 32); float4 p1b = *(const float4*)(xb + 36);
        float4 p2a = *(const float4*)(xb + 64); float4 p2b = *(const float4*)(xb + 68);

        __syncthreads();                   // prior half's B-frag reads done
        {   // async-stage this K-half's pk slabs: 8 x 1KB DMA per wave, zero VALU
            const u16* sh = pk_hi + h * 16384 + wbase + lane * 8;
            const u16* sl = pk_lo + h * 16384 + wbase + lane * 8;
            #pragma unroll
            for (int i = 0; i < 4; ++i) {
                gload_lds16(sh + i * 512, whi + wbase + i * 512);
                gload_lds16(sl + i * 512, wlo + wbase + i * 512);
            }
        }
        __syncthreads();                   // compiler-emitted vmcnt(0) drains the DMAs

        #pragma unroll
        for (int kb = 0; kb < 8; ++kb) {   // 8 K32 steps, barrier-free, 3-deep x prefetch
            s16x8 ah, al;
            split8(p0a, p0b, ah, al);
            p0a = p1a; p0b = p1b; p1a = p2a; p1b = p2b;
            if (kb < 5) {
                const float* nx = xb + (kb + 3) * 32;
                p2a = *(const float4*)(nx);
                p2b = *(const float4*)(nx + 4);
            }
            const int fq = (kb * 4 + kq) * 512 + fb;
            s16x8 bh0 = *(const s16x8*)&whi[fq];
            s16x8 bl0 = *(const s16x8*)&wlo[fq];
            s16x8 bh1 = *(const s16x8*)&whi[fq + 128];   // nt=1: +16 expert rows
            s16x8 bl1 = *(const s16x8*)&wlo[fq + 128];
            acc[0] = MFMA_B16(ah, bh0, acc[0]);   // hi*hi
            acc[0] = MFMA_B16(ah, bl0, acc[0]);   // hi*lo
            acc[0] = MFMA_B16(al, bh0, acc[0]);   // lo*hi
            acc[1] = MFMA_B16(ah, bh1, acc[1]);
            acc[1] = MFMA_B16(ah, bl1, acc[1]);
            acc[1] = MFMA_B16(al, bh1, acc[1]);
        }
    }

    // ---- logits to LDS plane [64 tok][PSTR] ----
    __syncthreads();
    #pragma unroll
    for (int nt = 0; nt < 2; ++nt)
        #pragma unroll
        for (int i = 0; i < 4; ++i)
            P[(tokG * 16 + kq * 4 + i) * PSTR + expG * 32 + nt * 16 + l15] = acc[nt][i];
    __syncthreads();

    // ---- E1: per (token tt, slice ss) local top-3 over 8 experts ----
    const int tt = tid & 63;
    const int ss = tid >> 6;
    float v[8];
    #pragma unroll
    for (int j = 0; j < 8; ++j) v[j] = P[tt * PSTR + ss * 8 + j];

    float m1 = -INFINITY, m2 = -INFINITY, m3 = -INFINITY;
    int   i1 = NEXP, i2 = NEXP, i3 = NEXP;
    #pragma unroll
    for (int j = 0; j < 8; ++j) {          // ascending e + strict > == lax.top_k tie-break
        float val = v[j]; int e = ss * 8 + j;
        if (val > m1)      { m3 = m2; i3 = i2; m2 = m1; i2 = i1; m1 = val; i1 = e; }
        else if (val > m2) { m3 = m2; i3 = i2; m2 = val; i2 = e; }
        else if (val > m3) { m3 = val; i3 = e; }
    }
    candv[tt * 25 + ss * 3 + 0] = m1; candi[tt * 25 + ss * 3 + 0] = i1;
    candv[tt * 25 + ss * 3 + 1] = m2; candi[tt * 25 + ss * 3 + 1] = i2;
    candv[tt * 25 + ss * 3 + 2] = m3; candi[tt * 25 + ss * 3 + 2] = i3;
    __syncthreads();

    // ---- E2: merge 24 candidates (slice-ascending insertion keeps low-index ties first) ----
    m1 = m2 = m3 = -INFINITY; i1 = i2 = i3 = NEXP;
    #pragma unroll
    for (int q = 0; q < 24; ++q) {
        float val = candv[tt * 25 + q]; int e = candi[tt * 25 + q];
        if (val > m1)      { m3 = m2; i3 = i2; m2 = m1; i2 = i1; m1 = val; i1 = e; }
        else if (val > m2) { m3 = m2; i3 = i2; m2 = val; i2 = e; }
        else if (val > m3) { m3 = val; i3 = e; }
    }

    float ex[8]; float ps = 0.f;
    #pragma unroll
    for (int j = 0; j < 8; ++j) { ex[j] = __expf(v[j] - m1); ps += ex[j]; }
    qsum[tt * 9 + ss] = ps;

    if (ss == 0) {                         // wave 0: gates + cooperative guard re-rank
        {   // default gates from MFMA logits
            const float ed  = __expf(m2 - m1);
            const float inv = 1.f / (1.f + ed);
            gateL[tt * 4 + 0] = inv;
            gateL[tt * 4 + 1] = ed * inv;
            ((int*)gateL)[tt * 4 + 2] = i1;
            ((int*)gateL)[tt * 4 + 3] = i2;
        }
        // near top-2/3 boundary: exact f32 re-rank, 64-lane cooperative per flagged token
        unsigned long long bmask = __ballot(m2 - m3 < TAU);
        while (bmask) {
            const int f = __ffsll(bmask) - 1;
            bmask &= bmask - 1;
            int id3[3];
            id3[0] = __shfl(i1, f); id3[1] = __shfl(i2, f); id3[2] = __shfl(i3, f);
            const float* xrow = x + (size_t)(tok0 + f) * RDIM + lane * 8;
            float4 a0 = *(const float4*)(xrow);
            float4 a1 = *(const float4*)(xrow + 4);
            float d[3];
            #pragma unroll
            for (int jj = 0; jj < 3; ++jj) {
                const float* wrow = w + (size_t)id3[jj] * RDIM + lane * 8;
                float4 b0 = *(const float4*)(wrow);
                float4 b1 = *(const float4*)(wrow + 4);
                float p = a0.x * b0.x;
                p = fmaf(a0.y, b0.y, p); p = fmaf(a0.z, b0.z, p); p = fmaf(a0.w, b0.w, p);
                p = fmaf(a1.x, b1.x, p); p = fmaf(a1.y, b1.y, p);
                p = fmaf(a1.z, b1.z, p); p = fmaf(a1.w, b1.w, p);
                #pragma unroll
                for (int off = 32; off; off >>= 1) p += __shfl_xor(p, off);
                d[jj] = p;
            }
            int b = 0;
            if (d[1] > d[0] || (d[1] == d[0] && id3[1] < id3[0])) b = 1;
            if (d[2] > d[b] || (d[2] == d[b] && id3[2] < id3[b])) b = 2;
            int sec;
            if (b == 0)      sec = (d[1] > d[2] || (d[1] == d[2] && id3[1] < id3[2])) ? 1 : 2;
            else if (b == 1) sec = (d[0] > d[2] || (d[0] == d[2] && id3[0] < id3[2])) ? 0 : 2;
            else             sec = (d[0] > d[1] || (d[0] == d[1] && id3[0] < id3[1])) ? 0 : 1;
            if (lane == f) {
                const float ed  = __expf(d[sec] - d[b]);
                const float inv = 1.f / (1.f + ed);
                gateL[f * 4 + 0] = inv;
                gateL[f * 4 + 1] = ed * inv;
                ((int*)gateL)[f * 4 + 2] = id3[b];
                ((int*)gateL)[f * 4 + 3] = id3[sec];
            }
        }
    }
    __syncthreads();

    // ---- E3: softmax denominator + probs in place ----
    float Z = 0.f;
    #pragma unroll
    for (int k = 0; k < 8; ++k) Z += qsum[tt * 9 + k];
    const float invZ = 1.f / Z;
    #pragma unroll
    for (int j = 0; j < 8; ++j) P[tt * PSTR + ss * 8 + j] = ex[j] * invZ;
    __syncthreads();

    // ---- E4: per-expert column sums for aux ----
    {
        const int e = tid & 63, tq = tid >> 6;
        float s = 0.f; unsigned cn = 0u;
        #pragma unroll
        for (int t = 0; t < 8; ++t) {
            float pv = P[(tq * 8 + t) * PSTR + e];
            s += pv; cn += (pv > 0.f) ? 1u : 0u;
        }
        atomicAdd(&s_aux[e], s);
        atomicAdd(&s_cnt[e], cn);
    }
    __syncthreads();
    if (tid < 64) {
        atomicAdd(aux_sum + tid, s_aux[tid]);
        atomicAdd(aux_cnt + tid, s_cnt[tid]);
    }

    // ---- OUT: wave handles 8 tokens, lane = r-chunk (coalesced 1KB stores) ----
    {
        const int e = lane;
        #pragma unroll
        for (int s2 = 0; s2 < 8; ++s2) {
            const int t2 = wv * 8 + s2;
            float4 g4 = *(float4*)&gateL[t2 * 4];       // broadcast read
            const float g1 = g4.x, g2 = g4.y;
            const int e1 = __float_as_int(g4.z), e2 = __float_as_int(g4.w);
            const float4* c1 = (const float4*)(cent + (size_t)e1 * RDIM);
            const float4* c2 = (const float4*)(cent + (size_t)e2 * RDIM);
            float4* op = (float4*)(out + (size_t)(tok0 + t2) * RDIM);
            float4 A0 = c1[e],      Bb0 = c2[e];
            float4 A1 = c1[e + 64], Bb1 = c2[e + 64];
            float4 o0, o1;
            o0.x = fmaf(g1, A0.x, g2 * Bb0.x); o0.y = fmaf(g1, A0.y, g2 * Bb0.y);
            o0.z = fmaf(g1, A0.z, g2 * Bb0.z); o0.w = fmaf(g1, A0.w, g2 * Bb0.w);
            o1.x = fmaf(g1, A1.x, g2 * Bb1.x); o1.y = fmaf(g1, A1.y, g2 * Bb1.y);
            o1.z = fmaf(g1, A1.z, g2 * Bb1.z); o1.w = fmaf(g1, A1.w, g2 * Bb1.w);
            op[e]      = o0;
            op[e + 64] = o1;
        }
    }
}

// ---------------- Fallback kernels (used only if ws too small) ----------------
__global__ __launch_bounds__(256) void centroid_kernel(
    const float* __restrict__ atoms,
    const float* __restrict__ cw,
    const float* __restrict__ cl,
    float* __restrict__ cent,
    float* __restrict__ aux_sum,
    unsigned* __restrict__ aux_cnt)
{
    __shared__ unsigned pack[NK];
    const int tid = threadIdx.x;
    if (blockIdx.x == 0 && tid < 64) { aux_sum[tid] = 0.f; aux_cnt[tid] = 0u; }
    centroid_body(blockIdx.x >> 1, blockIdx.x & 1, tid, atoms, cw, cl, cent, pack);
}

__global__ __launch_bounds__(256, 4) void moe_main(
    const float* __restrict__ x,
    const float* __restrict__ w,
    const float* __restrict__ cent,
    float* __restrict__ out,
    float* __restrict__ aux_sum,
    unsigned* __restrict__ aux_cnt)
{
    __shared__ u16 wlds[2 * 64 * LDQ];
    u16* whi = wlds;
    u16* wlo = wlds + 64 * LDQ;
    float* P     = (float*)wlds;
    float* candv = P + 64 * PSTR;
    int*   candi = (int*)(candv + 64 * 13);
    float* qsum  = (float*)(candi + 64 * 13);
    float* gateL = qsum + 64 * 5;
    __shared__ float s_aux[64];
    __shared__ unsigned s_cnt[64];

    const int tid  = threadIdx.x;
    const int lane = tid & 63;
    const int wave = tid >> 6;
    const int l15  = lane & 15;
    const int kgrp = (lane >> 4) << 3;
    const int tok0 = blockIdx.x * 64;

    if (tid < 64) { s_aux[tid] = 0.f; s_cnt[tid] = 0u; }

    f32x4 acc[4];
    #pragma unroll
    for (int nt = 0; nt < 4; ++nt) acc[nt] = (f32x4){0.f, 0.f, 0.f, 0.f};

    const float* xlane = x + (size_t)(tok0 + wave * 16 + l15) * RDIM + kgrp;
    const int wrow = tid >> 2;
    const int wseg = tid & 3;
    const float* wg = w + (size_t)wrow * RDIM + wseg * 32;
    const int woff = wrow * LDQ + wseg * 32;

    float4 preA[4], preB[4];
    #pragma unroll
    for (int i = 0; i < 4; ++i) {
        preA[i] = *(const float4*)(xlane + i * 32);
        preB[i] = *(const float4*)(xlane + i * 32 + 4);
    }

    #pragma unroll
    for (int q = 0; q < 4; ++q) {
        if (q) __syncthreads();
        {
            const float* wq = wg + q * 128;
            uint2 h2[2], l2[2];
            #pragma unroll
            for (int j = 0; j < 8; ++j) {
                float4 wvv = *(const float4*)(wq + j * 4);
                split_pack(wvv, h2[j & 1].x, h2[j & 1].y, l2[j & 1].x, l2[j & 1].y);
                if (j & 1) {
                    *(uint4*)&whi[woff + (j - 1) * 4] =
                        make_uint4(h2[0].x, h2[0].y, h2[1].x, h2[1].y);
                    *(uint4*)&wlo[woff + (j - 1) * 4] =
                        make_uint4(l2[0].x, l2[0].y, l2[1].x, l2[1].y);
                }
            }
        }
        __syncthreads();

        #pragma unroll
        for (int kb = 0; kb < 4; ++kb) {
            const int g = q * 4 + kb;
            s16x8 ah, al;
            split8(preA[g & 3], preB[g & 3], ah, al);
            if (g + 4 < 16) {
                const float* nx = xlane + (g + 4) * 32;
                preA[g & 3] = *(const float4*)(nx);
                preB[g & 3] = *(const float4*)(nx + 4);
            }
            const int kl = kb * 32 + kgrp;
            #pragma unroll
            for (int nt = 0; nt < 4; ++nt) {
                const int brow = nt * 16 + l15;
                s16x8 bh = *(const s16x8*)&whi[brow * LDQ + kl];
                s16x8 bl = *(const s16x8*)&wlo[brow * LDQ + kl];
                acc[nt] = MFMA_B16(ah, bh, acc[nt]);
                acc[nt] = MFMA_B16(ah, bl, acc[nt]);
                acc[nt] = MFMA_B16(al, bh, acc[nt]);
            }
        }
    }

    __syncthreads();
    #pragma unroll
    for (int nt = 0; nt < 4; ++nt)
        #pragma unroll
        for (int i = 0; i < 4; ++i)
            P[(wave * 16 + ((lane >> 4) << 2) + i) * PSTR + nt * 16 + l15] = acc[nt][i];
    __syncthreads();

    const int tt = tid & 63;
    const int ss = tid >> 6;
    float v[16];
    #pragma unroll
    for (int j = 0; j < 16; ++j) v[j] = P[tt * PSTR + ss * 16 + j];

    float m1 = -INFINITY, m2 = -INFINITY, m3 = -INFINITY;
    int   i1 = NEXP, i2 = NEXP, i3 = NEXP;
    #pragma unroll
    for (int j = 0; j < 16; ++j) {
        float val = v[j]; int e = ss * 16 + j;
        if (val > m1)      { m3 = m2; i3 = i2; m2 = m1; i2 = i1; m1 = val; i1 = e; }
        else if (val > m2) { m3 = m2; i3 = i2; m2 = val; i2 = e; }
        else if (val > m3) { m3 = val; i3 = e; }
    }
    candv[tt * 13 + ss * 3 + 0] = m1; candi[tt * 13 + ss * 3 + 0] = i1;
    candv[tt * 13 + ss * 3 + 1] = m2; candi[tt * 13 + ss * 3 + 1] = i2;
    candv[tt * 13 + ss * 3 + 2] = m3; candi[tt * 13 + ss * 3 + 2] = i3;
    __syncthreads();

    m1 = m2 = m3 = -INFINITY; i1 = i2 = i3 = NEXP;
    #pragma unroll
    for (int q = 0; q < 12; ++q) {
        float val = candv[tt * 13 + q]; int e = candi[tt * 13 + q];
        if (val > m1)      { m3 = m2; i3 = i2; m2 = m1; i2 = i1; m1 = val; i1 = e; }
        else if (val > m2) { m3 = m2; i3 = i2; m2 = val; i2 = e; }
        else if (val > m3) { m3 = val; i3 = e; }
    }

    float ex[16]; float ps = 0.f;
    #pragma unroll
    for (int j = 0; j < 16; ++j) { ex[j] = __expf(v[j] - m1); ps += ex[j]; }
    qsum[tt * 5 + ss] = ps;

    if (ss == 0) {
        {
            const float ed  = __expf(m2 - m1);
            const float inv = 1.f / (1.f + ed);
            gateL[tt * 4 + 0] = inv;
            gateL[tt * 4 + 1] = ed * inv;
            ((int*)gateL)[tt * 4 + 2] = i1;
            ((int*)gateL)[tt * 4 + 3] = i2;
        }
        unsigned long long bmask = __ballot(m2 - m3 < TAU);
        while (bmask) {
            const int f = __ffsll(bmask) - 1;
            bmask &= bmask - 1;
            int id3[3];
            id3[0] = __shfl(i1, f); id3[1] = __shfl(i2, f); id3[2] = __shfl(i3, f);
            const float* xrow = x + (size_t)(tok0 + f) * RDIM + lane * 8;
            float4 a0 = *(const float4*)(xrow);
            float4 a1 = *(const float4*)(xrow + 4);
            float d[3];
            #pragma unroll
            for (int jj = 0; jj < 3; ++jj) {
                const float* wrow2 = w + (size_t)id3[jj] * RDIM + lane * 8;
                float4 b0 = *(const float4*)(wrow2);
                float4 b1 = *(const float4*)(wrow2 + 4);
                float p = a0.x * b0.x;
                p = fmaf(a0.y, b0.y, p); p = fmaf(a0.z, b0.z, p); p = fmaf(a0.w, b0.w, p);
                p = fmaf(a1.x, b1.x, p); p = fmaf(a1.y, b1.y, p);
                p = fmaf(a1.z, b1.z, p); p = fmaf(a1.w, b1.w, p);
                #pragma unroll
                for (int off = 32; off; off >>= 1) p += __shfl_xor(p, off);
                d[jj] = p;
            }
            int b = 0;
            if (d[1] > d[0] || (d[1] == d[0] && id3[1] < id3[0])) b = 1;
            if (d[2] > d[b] || (d[2] == d[b] && id3[2] < id3[b])) b = 2;
            int sec;
            if (b == 0)      sec = (d[1] > d[2] || (d[1] == d[2] && id3[1] < id3[2])) ? 1 : 2;
            else if (b == 1) sec = (d[0] > d[2] || (d[0] == d[2] && id3[0] < id3[2])) ? 0 : 2;
            else             sec = (d[0] > d[1] || (d[0] == d[1] && id3[0] < id3[1])) ? 0 : 1;
            if (lane == f) {
                const float ed  = __expf(d[sec] - d[b]);
                const float inv = 1.f / (1.f + ed);
                gateL[f * 4 + 0] = inv;
                gateL[f * 4 + 1] = ed * inv;
                ((int*)gateL)[f * 4 + 2] = id3[b];
                ((int*)gateL)[f * 4 + 3] = id3[sec];
            }
        }
    }
    __syncthreads();

    float Z = 0.f;
    #pragma unroll
    for (int k = 0; k < 4; ++k) Z += qsum[tt * 5 + k];
    const float invZ = 1.f / Z;
    #pragma unroll
    for (int j = 0; j < 16; ++j) P[tt * PSTR + ss * 16 + j] = ex[j] * invZ;
    __syncthreads();

    {
        const int e = tid & 63, tq = tid >> 6;
        float s = 0.f; unsigned cn = 0u;
        #pragma unroll
        for (int t = 0; t < 16; ++t) {
            float pv = P[(tq * 16 + t) * PSTR + e];
            s += pv; cn += (pv > 0.f) ? 1u : 0u;
        }
        atomicAdd(&s_aux[e], s);
        atomicAdd(&s_cnt[e], cn);
    }
    __syncthreads();
    if (tid < 64) {
        atomicAdd(aux_sum + tid, s_aux[tid]);
        atomicAdd(aux_cnt + tid, s_cnt[tid]);
    }

    {
        const int e = lane;
        #pragma unroll
        for (int s2 = 0; s2 < 16; ++s2) {
            const int t2 = wave * 16 + s2;
            float4 g4 = *(float4*)&gateL[t2 * 4];
            const float g1 = g4.x, g2 = g4.y;
            const int e1 = __float_as_int(g4.z), e2 = __float_as_int(g4.w);
            const float4* c1 = (const float4*)(cent + (size_t)e1 * RDIM);
            const float4* c2 = (const float4*)(cent + (size_t)e2 * RDIM);
            float4* op = (float4*)(out + (size_t)(tok0 + t2) * RDIM);
            float4 A0 = c1[e],      Bb0 = c2[e];
            float4 A1 = c1[e + 64], Bb1 = c2[e + 64];
            float4 o0, o1;
            o0.x = fmaf(g1, A0.x, g2 * Bb0.x); o0.y = fmaf(g1, A0.y, g2 * Bb0.y);
            o0.z = fmaf(g1, A0.z, g2 * Bb0.z); o0.w = fmaf(g1, A0.w, g2 * Bb0.w);
            o1.x = fmaf(g1, A1.x, g2 * Bb1.x); o1.y = fmaf(g1, A1.y, g2 * Bb1.y);
            o1.z = fmaf(g1, A1.z, g2 * Bb1.z); o1.w = fmaf(g1, A1.w, g2 * Bb1.w);
            op[e]      = o0;
            op[e + 64] = o1;
        }
    }
}

// ---------------- Kernel C: aux loss finalize ----------------
__global__ __launch_bounds__(64) void aux_kernel(
    const float* __restrict__ sums,
    const unsigned* __restrict__ cnts,
    float* __restrict__ out_aux)
{
    const int e = threadIdx.x;
    float v = (sums[e] * (1.f / (float)TOKENS)) * ((float)cnts[e] * (1.f / (float)TOKENS));
    #pragma unroll
    for (int off = 32; off; off >>= 1) v += __shfl_xor(v, off);
    if (e == 0) out_aux[0] = (float)NEXP * v;
}

extern "C" void kernel_launch(void* const* d_in, const int* in_sizes, int n_in,
                              void* d_out, int out_size, void* d_ws, size_t ws_size,
                              hipStream_t stream) {
    const float* x     = (const float*)d_in[0];  // (8,4096,512)
    const float* rw    = (const float*)d_in[1];  // (64,512)
    const float* atoms = (const float*)d_in[2];  // (64,16,512)
    const float* cwts  = (const float*)d_in[3];  // (64,256,3)
    const float* clog  = (const float*)d_in[4];  // (64,256,3,16)
    float* out = (float*)d_out;
    float* out_aux = out + (size_t)TOKENS * RDIM;

    // ws: aux_sum[64]@0, aux_cnt[64]@256, cent@512 (128KB), pk_hi@131584 (64KB), pk_lo@197120
    float*    aux_sum = (float*)d_ws;
    unsigned* aux_cnt = (unsigned*)((char*)d_ws + 256);
    float*    cent    = (float*)((char*)d_ws + 512);
    u16*      pk_hi   = (u16*)((char*)d_ws + 512 + 131072);
    u16*      pk_lo   = (u16*)((char*)d_ws + 512 + 131072 + 65536);
    const bool fast = ws_size >= (size_t)(512 + 131072 + 2 * 65536);

    if (fast) {
        centroid_pack_kernel<<<160, 256, 0, stream>>>(atoms, cwts, clog, rw, cent,
                                                      pk_hi, pk_lo, aux_sum, aux_cnt);
        moe_fast4<<<512, 512, 0, stream>>>(x, pk_hi, pk_lo, rw, cent, out, aux_sum, aux_cnt);
    } else {
        centroid_kernel<<<128, 256, 0, stream>>>(atoms, cwts, clog, cent, aux_sum, aux_cnt);
        moe_main<<<512, 256, 0, stream>>>(x, rw, cent, out, aux_sum, aux_cnt);
    }
    aux_kernel<<<1, 64, 0, stream>>>(aux_sum, aux_cnt, out_aux);
}